// Round 7
// baseline (583.376 us; speedup 1.0000x reference)
//
#include <hip/hip_runtime.h>
#include <math.h>

#define NROWS 262144
#define DDIM  1024
#define EEXP  64
#define NDOCS 1024
#define BM    128
#define HB    64            // hist/scatter blocks
#define RPB   (NROWS / HB)  // rows per hist/scatter block

typedef __attribute__((ext_vector_type(8)))  __bf16 bf16x8;
typedef __attribute__((ext_vector_type(16))) float  f32x16;
typedef unsigned short ushort_t;
typedef unsigned int   uint_t;

// ws layout:
//   Whg ushort[EEXP*DDIM], Wlg ushort[EEXP*DDIM]
//   sorted_rows int[NROWS], offsets int[NDOCS+1], cnt int[NDOCS], cursor int[NDOCS]
//   pen_sum f32, uniq f32

__global__ __launch_bounds__(1024) void init_kernel(int* cnt, float* pen_sum, float* uniq) {
    const int t = threadIdx.x;
    cnt[t] = 0;
    if (t == 0) { pen_sum[0] = 0.0f; uniq[0] = 0.0f; }
}

// LDS-privatized histogram: HB blocks x RPB rows; <=NDOCS global atomics per block.
__global__ __launch_bounds__(256) void hist_kernel(const int* __restrict__ idx, int* __restrict__ cnt) {
    __shared__ int lh[NDOCS];
    const int t = threadIdx.x;
    for (int i = t; i < NDOCS; i += 256) lh[i] = 0;
    __syncthreads();
    const int base = blockIdx.x * RPB;
    for (int i = t; i < RPB; i += 256) atomicAdd(&lh[idx[base + i]], 1);
    __syncthreads();
    for (int i = t; i < NDOCS; i += 256) {
        const int c = lh[i];
        if (c) atomicAdd(&cnt[i], c);
    }
}

__global__ __launch_bounds__(1024) void scan_kernel(const int* __restrict__ cnt,
                                                    int* __restrict__ offsets,
                                                    int* __restrict__ cursor) {
    __shared__ int sbuf[NDOCS];
    const int t = threadIdx.x;
    const int my = cnt[t];
    sbuf[t] = my;
    __syncthreads();
    for (int off = 1; off < NDOCS; off <<= 1) {
        int add = (t >= off) ? sbuf[t - off] : 0;
        __syncthreads();
        sbuf[t] += add;
        __syncthreads();
    }
    const int excl = sbuf[t] - my;
    offsets[t] = excl;
    cursor[t]  = excl;
    if (t == NDOCS - 1) offsets[NDOCS] = sbuf[t];
}

// Block-range-reservation scatter: count locally, reserve one global range per
// (block,doc), place rows via LDS cursors. <=NDOCS global atomics per block.
__global__ __launch_bounds__(256) void scatter_kernel(const int* __restrict__ idx,
                                                      int* __restrict__ cursor,
                                                      int* __restrict__ sorted_rows) {
    __shared__ int lh[NDOCS];
    __shared__ int lbase[NDOCS];
    __shared__ int lc[NDOCS];
    const int t = threadIdx.x;
    for (int i = t; i < NDOCS; i += 256) { lh[i] = 0; lc[i] = 0; }
    __syncthreads();
    const int base = blockIdx.x * RPB;
    for (int i = t; i < RPB; i += 256) atomicAdd(&lh[idx[base + i]], 1);
    __syncthreads();
    for (int i = t; i < NDOCS; i += 256) {
        const int c = lh[i];
        if (c) lbase[i] = atomicAdd(&cursor[i], c);
    }
    __syncthreads();
    for (int i = t; i < RPB; i += 256) {
        const int r = base + i;
        const int d = idx[r];
        const int p = atomicAdd(&lc[d], 1);
        sorted_rows[lbase[d] + p] = r;
    }
}

__global__ __launch_bounds__(256) void convw_kernel(const float* __restrict__ Wg,
                                                    ushort_t* __restrict__ Whg,
                                                    ushort_t* __restrict__ Wlg) {
    const int i = blockIdx.x * 256 + threadIdx.x;
    const float wv = Wg[i];
    const uint_t b = __float_as_uint(wv);
    const float lov = wv - __uint_as_float(b & 0xFFFF0000u);
    Whg[i] = (ushort_t)(b >> 16);
    Wlg[i] = (ushort_t)(__float_as_uint(lov) >> 16);
}

// Zero-LDS, zero-barrier MFMA GEMM. 4 waves x 32 rows, 32x32x16 bf16 split-hi/lo.
// x: per-lane register-direct, one 4-tile super prefetched ahead (dbuf).
// W: per-lane fragments from L2 (256 KB hot), pipelined one tile ahead.
// Each wave starts at rotated k-phase (4*bix+w)&7; fp32 accumulate is exact
// per-element regardless of order.
struct XT { float4 a0, a1, a2, a3; };
struct XS { XT t0, t1, t2, t3; };
struct WT { bf16x8 h00, h01, h10, h11, m00, m01, m10, m11; };

__global__ __launch_bounds__(256, 2) void gemm_softmax_kernel(
    const float*    __restrict__ x,
    const ushort_t* __restrict__ Whg,
    const ushort_t* __restrict__ Wlg,
    float*          __restrict__ w_out)
{
    const int t   = threadIdx.x;
    const int w   = t >> 6;
    const int l   = t & 63;
    const int cl  = l & 31;     // A-row-in-wave-tile / B-col / D-col
    const int hi  = l >> 5;     // k-half selector
    const size_t br = (size_t)blockIdx.x * BM;

    const float*    xrow = x   + (br + (size_t)(w * 32 + cl)) * DDIM + 8 * hi;
    const ushort_t* whp0 = Whg + (size_t)cl        * DDIM + 8 * hi;
    const ushort_t* whp1 = Whg + (size_t)(cl + 32) * DDIM + 8 * hi;
    const ushort_t* wlp0 = Wlg + (size_t)cl        * DDIM + 8 * hi;
    const ushort_t* wlp1 = Wlg + (size_t)(cl + 32) * DDIM + 8 * hi;

    f32x16 acc0 = {};
    f32x16 acc1 = {};
    XS xA, xB;
    WT wv, wn;

    union u8b { uint_t u[4]; bf16x8 v; };

#define LOAD_XT(DST, T) do {                                                           \
        const float* p_ = xrow + (size_t)(T) * 32;                                     \
        DST.a0 = *(const float4*)(p_);                                                 \
        DST.a1 = *(const float4*)(p_ + 4);                                             \
        DST.a2 = *(const float4*)(p_ + 16);                                            \
        DST.a3 = *(const float4*)(p_ + 20);                                            \
    } while (0)

#define LOAD_XS(S, SUP) do {                                                           \
        LOAD_XT(S.t0, 4 * (SUP) + 0);                                                  \
        LOAD_XT(S.t1, 4 * (SUP) + 1);                                                  \
        LOAD_XT(S.t2, 4 * (SUP) + 2);                                                  \
        LOAD_XT(S.t3, 4 * (SUP) + 3);                                                  \
    } while (0)

#define LOAD_WT(DST, T) do {                                                           \
        const size_t o_ = (size_t)(T) * 32;                                            \
        DST.h00 = *(const bf16x8*)(whp0 + o_);                                         \
        DST.h01 = *(const bf16x8*)(whp0 + o_ + 16);                                    \
        DST.h10 = *(const bf16x8*)(whp1 + o_);                                         \
        DST.h11 = *(const bf16x8*)(whp1 + o_ + 16);                                    \
        DST.m00 = *(const bf16x8*)(wlp0 + o_);                                         \
        DST.m01 = *(const bf16x8*)(wlp0 + o_ + 16);                                    \
        DST.m10 = *(const bf16x8*)(wlp1 + o_);                                         \
        DST.m11 = *(const bf16x8*)(wlp1 + o_ + 16);                                    \
    } while (0)

#define SPLIT8(A, B, AH, AL) do {                                                      \
        const float av_[8] = {A.x, A.y, A.z, A.w, B.x, B.y, B.z, B.w};                 \
        _Pragma("unroll")                                                              \
        for (int p_ = 0; p_ < 4; ++p_) {                                               \
            const uint_t b0_ = __float_as_uint(av_[2 * p_]);                           \
            const uint_t b1_ = __float_as_uint(av_[2 * p_ + 1]);                       \
            AH.u[p_] = (b0_ >> 16) | (b1_ & 0xFFFF0000u);                              \
            const float l0_ = av_[2 * p_]     - __uint_as_float(b0_ & 0xFFFF0000u);    \
            const float l1_ = av_[2 * p_ + 1] - __uint_as_float(b1_ & 0xFFFF0000u);    \
            AL.u[p_] = (__float_as_uint(l0_) >> 16) | (__float_as_uint(l1_) & 0xFFFF0000u); \
        } } while (0)

#define COMPUTE_T(XV, WV) do {                                                         \
        u8b ah0, al0, ah1, al1;                                                        \
        SPLIT8(XV.a0, XV.a1, ah0, al0);                                                \
        SPLIT8(XV.a2, XV.a3, ah1, al1);                                                \
        acc0 = __builtin_amdgcn_mfma_f32_32x32x16_bf16(ah0.v, WV.h00, acc0, 0, 0, 0);  \
        acc1 = __builtin_amdgcn_mfma_f32_32x32x16_bf16(ah0.v, WV.h10, acc1, 0, 0, 0);  \
        acc0 = __builtin_amdgcn_mfma_f32_32x32x16_bf16(ah0.v, WV.m00, acc0, 0, 0, 0);  \
        acc1 = __builtin_amdgcn_mfma_f32_32x32x16_bf16(ah0.v, WV.m10, acc1, 0, 0, 0);  \
        acc0 = __builtin_amdgcn_mfma_f32_32x32x16_bf16(al0.v, WV.h00, acc0, 0, 0, 0);  \
        acc1 = __builtin_amdgcn_mfma_f32_32x32x16_bf16(al0.v, WV.h10, acc1, 0, 0, 0);  \
        acc0 = __builtin_amdgcn_mfma_f32_32x32x16_bf16(ah1.v, WV.h01, acc0, 0, 0, 0);  \
        acc1 = __builtin_amdgcn_mfma_f32_32x32x16_bf16(ah1.v, WV.h11, acc1, 0, 0, 0);  \
        acc0 = __builtin_amdgcn_mfma_f32_32x32x16_bf16(ah1.v, WV.m01, acc0, 0, 0, 0);  \
        acc1 = __builtin_amdgcn_mfma_f32_32x32x16_bf16(ah1.v, WV.m11, acc1, 0, 0, 0);  \
        acc0 = __builtin_amdgcn_mfma_f32_32x32x16_bf16(al1.v, WV.h01, acc0, 0, 0, 0);  \
        acc1 = __builtin_amdgcn_mfma_f32_32x32x16_bf16(al1.v, WV.h11, acc1, 0, 0, 0);  \
    } while (0)

// One 4-tile super at phase s; optionally prefetch x for the next super.
#define SUPER(XC, XN, PF_X) do {                                                       \
        const int sn_ = (s + 1) & 7;                                                   \
        if (PF_X) LOAD_XS(XN, sn_);                                                    \
        LOAD_WT(wn, 4 * s + 1); COMPUTE_T(XC.t0, wv);                                  \
        LOAD_WT(wv, 4 * s + 2); COMPUTE_T(XC.t1, wn);                                  \
        LOAD_WT(wn, 4 * s + 3); COMPUTE_T(XC.t2, wv);                                  \
        LOAD_WT(wv, 4 * sn_);   COMPUTE_T(XC.t3, wn);                                  \
        s = sn_;                                                                       \
    } while (0)

    // rotated k-phase start per wave
    int s = (int)((blockIdx.x * 4 + w) & 7);

    LOAD_XS(xA, s);
    LOAD_WT(wv, 4 * s);

    SUPER(xA, xB, 1);
    SUPER(xB, xA, 1);
    SUPER(xA, xB, 1);
    SUPER(xB, xA, 1);
    SUPER(xA, xB, 1);
    SUPER(xB, xA, 1);
    SUPER(xA, xB, 1);
    SUPER(xB, xA, 0);

    // In-register softmax. D-layout: col = lane&31, row = (r&3) + 8*(r>>2) + 4*hi.
    const size_t orow_base = br + (size_t)w * 32;
    #pragma unroll
    for (int r = 0; r < 16; ++r) {
        const int row = (r & 3) + 8 * (r >> 2) + 4 * hi;
        const float v0 = acc0[r];
        const float v1 = acc1[r];
        float m = fmaxf(v0, v1);
        m = fmaxf(m, __shfl_xor(m, 1));
        m = fmaxf(m, __shfl_xor(m, 2));
        m = fmaxf(m, __shfl_xor(m, 4));
        m = fmaxf(m, __shfl_xor(m, 8));
        m = fmaxf(m, __shfl_xor(m, 16));
        const float e0 = __expf(v0 - m);
        const float e1 = __expf(v1 - m);
        float sden = e0 + e1;
        sden += __shfl_xor(sden, 1);
        sden += __shfl_xor(sden, 2);
        sden += __shfl_xor(sden, 4);
        sden += __shfl_xor(sden, 8);
        sden += __shfl_xor(sden, 16);
        const float inv = 1.0f / sden;
        float* wo = w_out + (orow_base + row) * EEXP;
        wo[cl]      = e0 * inv;
        wo[32 + cl] = e1 * inv;
    }
#undef LOAD_XT
#undef LOAD_XS
#undef LOAD_WT
#undef SPLIT8
#undef COMPUTE_T
#undef SUPER
}

// One block per doc. Row list prefetched to LDS to break the load->load chain.
__global__ __launch_bounds__(256) void segsum_kernel(
    const float* __restrict__ w,
    const int*   __restrict__ sorted_rows,
    const int*   __restrict__ offsets,
    float*       __restrict__ pen_sum,
    float*       __restrict__ uniq)
{
    __shared__ int rows_s[512];
    __shared__ float ls1[4][64], ls2[4][64];

    const int d  = blockIdx.x;
    const int t  = threadIdx.x;
    const int e  = t & 63;
    const int rg = t >> 6;
    const int start = offsets[d];
    const int end   = offsets[d + 1];
    const int n     = end - start;

    for (int i = t; i < n && i < 512; i += 256) rows_s[i] = sorted_rows[start + i];
    __syncthreads();

    float s1 = 0.0f, s2 = 0.0f;
    for (int i = rg; i < n; i += 4) {
        const int row = (i < 512) ? rows_s[i] : sorted_rows[start + i];
        const float v = w[(size_t)row * EEXP + e];
        s1 += v;
        s2 += v * v;
    }

    ls1[rg][e] = s1;
    ls2[rg][e] = s2;
    __syncthreads();

    if (t < 64) {
        const float a = ls1[0][e] + ls1[1][e] + ls1[2][e] + ls1[3][e];
        const float b = ls2[0][e] + ls2[1][e] + ls2[2][e] + ls2[3][e];
        const float safe = fmaxf((float)n, 1.0f);
        float contrib = b - a * a / safe;
        #pragma unroll
        for (int off = 32; off > 0; off >>= 1)
            contrib += __shfl_down(contrib, off);
        if (e == 0) {
            if (n > 1) atomicAdd(pen_sum, contrib / (safe * (float)EEXP));
            if (n > 0) atomicAdd(uniq, 1.0f);
        }
    }
}

__global__ void final_kernel(const float* __restrict__ pen_sum,
                             const float* __restrict__ uniq,
                             float* __restrict__ pen_out) {
    pen_out[0] = pen_sum[0] / uniq[0];
}

extern "C" void kernel_launch(void* const* d_in, const int* in_sizes, int n_in,
                              void* d_out, int out_size, void* d_ws, size_t ws_size,
                              hipStream_t stream) {
    const float* x   = (const float*)d_in[0];
    const int*   idx = (const int*)d_in[1];
    const float* Wg  = (const float*)d_in[2];

    float* out   = (float*)d_out;
    float* w_out = out;                                  // NROWS*EEXP floats
    float* pen   = out + (size_t)NROWS * EEXP;           // 1 float

    ushort_t* Whg = (ushort_t*)d_ws;
    ushort_t* Wlg = Whg + (size_t)EEXP * DDIM;
    int* sorted_rows = (int*)(Wlg + (size_t)EEXP * DDIM);
    int* offsets     = sorted_rows + NROWS;
    int* cnt         = offsets + NDOCS + 1;
    int* cursor      = cnt + NDOCS;
    float* pen_sum   = (float*)(cursor + NDOCS);
    float* uniq      = pen_sum + 1;

    init_kernel<<<1, 1024, 0, stream>>>(cnt, pen_sum, uniq);
    hist_kernel<<<HB, 256, 0, stream>>>(idx, cnt);
    scan_kernel<<<1, 1024, 0, stream>>>(cnt, offsets, cursor);
    scatter_kernel<<<HB, 256, 0, stream>>>(idx, cursor, sorted_rows);
    convw_kernel<<<(EEXP * DDIM) / 256, 256, 0, stream>>>(Wg, Whg, Wlg);
    gemm_softmax_kernel<<<NROWS / BM, 256, 0, stream>>>(x, Whg, Wlg, w_out);
    segsum_kernel<<<NDOCS, 256, 0, stream>>>(w_out, sorted_rows, offsets, pen_sum, uniq);
    final_kernel<<<1, 1, 0, stream>>>(pen_sum, uniq, pen);
}

// Round 8
// 371.064 us; speedup vs baseline: 1.5722x; 1.5722x over previous
//
#include <hip/hip_runtime.h>
#include <math.h>

#define NROWS 262144
#define DDIM  1024
#define EEXP  64
#define NDOCS 1024
#define BM    128
#define BK    32
#define HB    64            // hist/scatter blocks
#define RPB   (NROWS / HB)  // rows per hist/scatter block

typedef __attribute__((ext_vector_type(8)))  __bf16 bf16x8;
typedef __attribute__((ext_vector_type(16))) float  f32x16;
typedef unsigned short ushort_t;
typedef unsigned int   uint_t;

// ws layout:
//   Whg ushort[EEXP*DDIM], Wlg ushort[EEXP*DDIM]
//   sorted_rows int[NROWS], offsets int[NDOCS+1], cnt int[NDOCS], cursor int[NDOCS]
//   pen_sum f32, uniq f32

__global__ __launch_bounds__(1024) void init_kernel(int* cnt, float* pen_sum, float* uniq) {
    const int t = threadIdx.x;
    cnt[t] = 0;
    if (t == 0) { pen_sum[0] = 0.0f; uniq[0] = 0.0f; }
}

// LDS-privatized histogram: <=NDOCS global atomics per block.
__global__ __launch_bounds__(256) void hist_kernel(const int* __restrict__ idx, int* __restrict__ cnt) {
    __shared__ int lh[NDOCS];
    const int t = threadIdx.x;
    for (int i = t; i < NDOCS; i += 256) lh[i] = 0;
    __syncthreads();
    const int base = blockIdx.x * RPB;
    for (int i = t; i < RPB; i += 256) atomicAdd(&lh[idx[base + i]], 1);
    __syncthreads();
    for (int i = t; i < NDOCS; i += 256) {
        const int c = lh[i];
        if (c) atomicAdd(&cnt[i], c);
    }
}

__global__ __launch_bounds__(1024) void scan_kernel(const int* __restrict__ cnt,
                                                    int* __restrict__ offsets,
                                                    int* __restrict__ cursor) {
    __shared__ int sbuf[NDOCS];
    const int t = threadIdx.x;
    const int my = cnt[t];
    sbuf[t] = my;
    __syncthreads();
    for (int off = 1; off < NDOCS; off <<= 1) {
        int add = (t >= off) ? sbuf[t - off] : 0;
        __syncthreads();
        sbuf[t] += add;
        __syncthreads();
    }
    const int excl = sbuf[t] - my;
    offsets[t] = excl;
    cursor[t]  = excl;
    if (t == NDOCS - 1) offsets[NDOCS] = sbuf[t];
}

// Block-range-reservation scatter: <=NDOCS global atomics per block.
__global__ __launch_bounds__(256) void scatter_kernel(const int* __restrict__ idx,
                                                      int* __restrict__ cursor,
                                                      int* __restrict__ sorted_rows) {
    __shared__ int lh[NDOCS];
    __shared__ int lbase[NDOCS];
    __shared__ int lc[NDOCS];
    const int t = threadIdx.x;
    for (int i = t; i < NDOCS; i += 256) { lh[i] = 0; lc[i] = 0; }
    __syncthreads();
    const int base = blockIdx.x * RPB;
    for (int i = t; i < RPB; i += 256) atomicAdd(&lh[idx[base + i]], 1);
    __syncthreads();
    for (int i = t; i < NDOCS; i += 256) {
        const int c = lh[i];
        if (c) lbase[i] = atomicAdd(&cursor[i], c);
    }
    __syncthreads();
    for (int i = t; i < RPB; i += 256) {
        const int r = base + i;
        const int d = idx[r];
        const int p = atomicAdd(&lc[d], 1);
        sorted_rows[lbase[d] + p] = r;
    }
}

__global__ __launch_bounds__(256) void convw_kernel(const float* __restrict__ Wg,
                                                    ushort_t* __restrict__ Whg,
                                                    ushort_t* __restrict__ Wlg) {
    const int i = blockIdx.x * 256 + threadIdx.x;
    const float wv = Wg[i];
    const uint_t b = __float_as_uint(wv);
    const float lov = wv - __uint_as_float(b & 0xFFFF0000u);
    Whg[i] = (ushort_t)(b >> 16);
    Wlg[i] = (ushort_t)(__float_as_uint(lov) >> 16);
}

__device__ __forceinline__ void gl2lds16(const float* g, float* l) {
    __builtin_amdgcn_global_load_lds(
        (const __attribute__((address_space(1))) void*)g,
        (__attribute__((address_space(3))) void*)l,
        16, 0, 0);
}

#define VMCNT(N)  asm volatile("s_waitcnt vmcnt(" #N ")" ::: "memory")
#define LGKM0()   asm volatile("s_waitcnt lgkmcnt(0)" ::: "memory")
#define BAR()     do { __builtin_amdgcn_s_barrier(); asm volatile("" ::: "memory"); } while (0)

// MFMA GEMM, BM=128, BK=32, 4 waves, 32x32x16 bf16 split-hi/lo (3 products).
// DEPTH-2 x prefetch: xs triple-buffered; X(t+2) issued at iter t, waited at
// iter t+2 (vmcnt(10) keeps X(t+2)4 + W(t+2)2 + X(t+1)4) -> ~2 compute phases
// of HBM latency tolerance. W 2-deep through named reg sets A/B; the same
// vmcnt(10) guarantees W(t+1) regs landed, so ds_write needs no extra wait.
__global__ __launch_bounds__(256) void gemm_softmax_kernel(
    const float*    __restrict__ x,
    const ushort_t* __restrict__ Whg,
    const ushort_t* __restrict__ Wlg,
    float*          __restrict__ w_out)
{
    __shared__ float    xs[3][BM * BK];       // 3 x 16 KB; row stride 32 f32, unit ^= row&7
    __shared__ ushort_t whs[2][EEXP * 40];    // 2 x 5 KB, row stride 40 ushort
    __shared__ ushort_t wls[2][EEXP * 40];

    const int t   = threadIdx.x;
    const int w   = t >> 6;
    const int l   = t & 63;
    const int cl  = l & 31;
    const int hi  = l >> 5;
    const size_t br = (size_t)blockIdx.x * BM;

    const int lrow  = l >> 3;
    const int lunit = l & 7;

    const int se  = t >> 2;
    const int skq = t & 3;

    f32x16 acc0 = {};
    f32x16 acc1 = {};
    uint4 whA, wlA, whB, wlB;

    union u8b { uint_t u[4]; bf16x8 v; };

#define LOAD_W(WH, WL, k0) do {                                                        \
        WH = *(const uint4*)(Whg + (size_t)se * DDIM + (k0) + skq * 8);                \
        WL = *(const uint4*)(Wlg + (size_t)se * DDIM + (k0) + skq * 8);                \
    } while (0)

#define STAGE_X(XB, k0) do {                                                           \
        float* xb_ = XB;                                                               \
        _Pragma("unroll")                                                              \
        for (int i_ = 0; i_ < 4; ++i_) {                                               \
            const int chunk_ = w * 4 + i_;                                             \
            const int row_   = chunk_ * 8 + lrow;                                      \
            const float* gp_ = x + (br + row_) * DDIM + (k0) + ((lunit ^ (row_ & 7)) * 4); \
            gl2lds16(gp_, xb_ + chunk_ * 256);                                         \
        } } while (0)

#define WRITE_W(SLOT, WH, WL) do {                                                     \
        *(uint4*)(whs[SLOT] + se * 40 + skq * 8) = WH;                                 \
        *(uint4*)(wls[SLOT] + se * 40 + skq * 8) = WL;                                 \
    } while (0)

#define SPLIT8(A, B, AH, AL) do {                                                      \
        const float av_[8] = {A.x, A.y, A.z, A.w, B.x, B.y, B.z, B.w};                 \
        _Pragma("unroll")                                                              \
        for (int p_ = 0; p_ < 4; ++p_) {                                               \
            const uint_t b0_ = __float_as_uint(av_[2 * p_]);                           \
            const uint_t b1_ = __float_as_uint(av_[2 * p_ + 1]);                       \
            AH.u[p_] = (b0_ >> 16) | (b1_ & 0xFFFF0000u);                              \
            const float l0_ = av_[2 * p_]     - __uint_as_float(b0_ & 0xFFFF0000u);    \
            const float l1_ = av_[2 * p_ + 1] - __uint_as_float(b1_ & 0xFFFF0000u);    \
            AL.u[p_] = (__float_as_uint(l0_) >> 16) | (__float_as_uint(l1_) & 0xFFFF0000u); \
        } } while (0)

#define COMPUTE(XB, SLOT) do {                                                         \
        const float* xb_ = XB;                                                         \
        const int arow_ = w * 32 + cl;                                                 \
        const int sw7_  = arow_ & 7;                                                   \
        const float4 a0_ = *(const float4*)&xb_[arow_ * 32 + (((2*hi + 0) ^ sw7_) * 4)]; \
        const float4 a1_ = *(const float4*)&xb_[arow_ * 32 + (((2*hi + 1) ^ sw7_) * 4)]; \
        const float4 a2_ = *(const float4*)&xb_[arow_ * 32 + (((4 + 2*hi + 0) ^ sw7_) * 4)]; \
        const float4 a3_ = *(const float4*)&xb_[arow_ * 32 + (((4 + 2*hi + 1) ^ sw7_) * 4)]; \
        u8b ah0, al0, ah1, al1;                                                        \
        SPLIT8(a0_, a1_, ah0, al0);                                                    \
        SPLIT8(a2_, a3_, ah1, al1);                                                    \
        const int ko_ = 8 * hi;                                                        \
        const bf16x8 bh00 = *(const bf16x8*)(whs[SLOT] + (cl)      * 40 +      ko_);   \
        const bf16x8 bh01 = *(const bf16x8*)(whs[SLOT] + (cl)      * 40 + 16 + ko_);   \
        const bf16x8 bh10 = *(const bf16x8*)(whs[SLOT] + (32 + cl) * 40 +      ko_);   \
        const bf16x8 bh11 = *(const bf16x8*)(whs[SLOT] + (32 + cl) * 40 + 16 + ko_);   \
        const bf16x8 bl00 = *(const bf16x8*)(wls[SLOT] + (cl)      * 40 +      ko_);   \
        const bf16x8 bl01 = *(const bf16x8*)(wls[SLOT] + (cl)      * 40 + 16 + ko_);   \
        const bf16x8 bl10 = *(const bf16x8*)(wls[SLOT] + (32 + cl) * 40 +      ko_);   \
        const bf16x8 bl11 = *(const bf16x8*)(wls[SLOT] + (32 + cl) * 40 + 16 + ko_);   \
        acc0 = __builtin_amdgcn_mfma_f32_32x32x16_bf16(ah0.v, bh00, acc0, 0, 0, 0);    \
        acc1 = __builtin_amdgcn_mfma_f32_32x32x16_bf16(ah0.v, bh10, acc1, 0, 0, 0);    \
        acc0 = __builtin_amdgcn_mfma_f32_32x32x16_bf16(ah0.v, bl00, acc0, 0, 0, 0);    \
        acc1 = __builtin_amdgcn_mfma_f32_32x32x16_bf16(ah0.v, bl10, acc1, 0, 0, 0);    \
        acc0 = __builtin_amdgcn_mfma_f32_32x32x16_bf16(al0.v, bh00, acc0, 0, 0, 0);    \
        acc1 = __builtin_amdgcn_mfma_f32_32x32x16_bf16(al0.v, bh10, acc1, 0, 0, 0);    \
        acc0 = __builtin_amdgcn_mfma_f32_32x32x16_bf16(ah1.v, bh01, acc0, 0, 0, 0);    \
        acc1 = __builtin_amdgcn_mfma_f32_32x32x16_bf16(ah1.v, bh11, acc1, 0, 0, 0);    \
        acc0 = __builtin_amdgcn_mfma_f32_32x32x16_bf16(ah1.v, bl01, acc0, 0, 0, 0);    \
        acc1 = __builtin_amdgcn_mfma_f32_32x32x16_bf16(ah1.v, bl11, acc1, 0, 0, 0);    \
        acc0 = __builtin_amdgcn_mfma_f32_32x32x16_bf16(al1.v, bh01, acc0, 0, 0, 0);    \
        acc1 = __builtin_amdgcn_mfma_f32_32x32x16_bf16(al1.v, bh11, acc1, 0, 0, 0);    \
    } while (0)

    // ---- prologue ----
    // issue order: W(0)->A [2], X(0) [4], W(1)->B [2], X(1) [4]
    LOAD_W(whA, wlA, 0);
    STAGE_X(xs[0], 0);
    LOAD_W(whB, wlB, BK);
    STAGE_X(xs[1], BK);
    VMCNT(6);                 // keep [B2, X(1)4]: W(0)+X(0) landed
    WRITE_W(0, whA, wlA);
    LGKM0(); BAR();

    // ---- main loop: iters 0..29, pair-unrolled (even: load->A write B; odd: load->B write A) ----
    #pragma unroll 1
    for (int tp = 0; tp < 15; ++tp) {
        const int te = 2 * tp;
        {   // iter te (even)
            LOAD_W(whA, wlA, (te + 2) * BK);
            STAGE_X(xs[(te + 2) % 3], (te + 2) * BK);
            VMCNT(10);                      // keep X(t+2)4+W(t+2)2+X(t+1)4: X(t) landed, W(t+1) regs landed
            BAR();
            COMPUTE(xs[te % 3], te & 1);
            WRITE_W((te + 1) & 1, whB, wlB);
            LGKM0(); BAR();
        }
        {   // iter te+1 (odd)
            const int to = te + 1;
            LOAD_W(whB, wlB, (to + 2) * BK);
            STAGE_X(xs[(to + 2) % 3], (to + 2) * BK);
            VMCNT(10);
            BAR();
            COMPUTE(xs[to % 3], to & 1);
            WRITE_W((to + 1) & 1, whA, wlA);
            LGKM0(); BAR();
        }
    }
    // ---- iter 30 (even; nothing new to issue; write B = W(31)) ----
    VMCNT(6);                 // keep [W(31)2, X(31)4]: X(30) landed
    BAR();
    COMPUTE(xs[0], 0);        // 30%3=0, 30&1=0
    VMCNT(4);                 // keep X(31)4: W(31) regs landed
    WRITE_W(1, whB, wlB);
    LGKM0(); BAR();
    // ---- iter 31 ----
    VMCNT(0);
    BAR();
    COMPUTE(xs[1], 1);        // 31%3=1, 31&1=1

    // In-register softmax. D-layout: col = lane&31, row = (r&3) + 8*(r>>2) + 4*hi.
    const size_t orow_base = br + (size_t)w * 32;
    #pragma unroll
    for (int r = 0; r < 16; ++r) {
        const int row = (r & 3) + 8 * (r >> 2) + 4 * hi;
        const float v0 = acc0[r];
        const float v1 = acc1[r];
        float m = fmaxf(v0, v1);
        m = fmaxf(m, __shfl_xor(m, 1));
        m = fmaxf(m, __shfl_xor(m, 2));
        m = fmaxf(m, __shfl_xor(m, 4));
        m = fmaxf(m, __shfl_xor(m, 8));
        m = fmaxf(m, __shfl_xor(m, 16));
        const float e0 = __expf(v0 - m);
        const float e1 = __expf(v1 - m);
        float s = e0 + e1;
        s += __shfl_xor(s, 1);
        s += __shfl_xor(s, 2);
        s += __shfl_xor(s, 4);
        s += __shfl_xor(s, 8);
        s += __shfl_xor(s, 16);
        const float inv = 1.0f / s;
        float* wo = w_out + (orow_base + row) * EEXP;
        wo[cl]      = e0 * inv;
        wo[32 + cl] = e1 * inv;
    }
#undef LOAD_W
#undef STAGE_X
#undef WRITE_W
#undef SPLIT8
#undef COMPUTE
}

// One block per doc. Row list prefetched to LDS to break the load->load chain.
__global__ __launch_bounds__(256) void segsum_kernel(
    const float* __restrict__ w,
    const int*   __restrict__ sorted_rows,
    const int*   __restrict__ offsets,
    float*       __restrict__ pen_sum,
    float*       __restrict__ uniq)
{
    __shared__ int rows_s[512];
    __shared__ float ls1[4][64], ls2[4][64];

    const int d  = blockIdx.x;
    const int t  = threadIdx.x;
    const int e  = t & 63;
    const int rg = t >> 6;
    const int start = offsets[d];
    const int end   = offsets[d + 1];
    const int n     = end - start;

    for (int i = t; i < n && i < 512; i += 256) rows_s[i] = sorted_rows[start + i];
    __syncthreads();

    float s1 = 0.0f, s2 = 0.0f;
    for (int i = rg; i < n; i += 4) {
        const int row = (i < 512) ? rows_s[i] : sorted_rows[start + i];
        const float v = w[(size_t)row * EEXP + e];
        s1 += v;
        s2 += v * v;
    }

    ls1[rg][e] = s1;
    ls2[rg][e] = s2;
    __syncthreads();

    if (t < 64) {
        const float a = ls1[0][e] + ls1[1][e] + ls1[2][e] + ls1[3][e];
        const float b = ls2[0][e] + ls2[1][e] + ls2[2][e] + ls2[3][e];
        const float safe = fmaxf((float)n, 1.0f);
        float contrib = b - a * a / safe;
        #pragma unroll
        for (int off = 32; off > 0; off >>= 1)
            contrib += __shfl_down(contrib, off);
        if (e == 0) {
            if (n > 1) atomicAdd(pen_sum, contrib / (safe * (float)EEXP));
            if (n > 0) atomicAdd(uniq, 1.0f);
        }
    }
}

__global__ void final_kernel(const float* __restrict__ pen_sum,
                             const float* __restrict__ uniq,
                             float* __restrict__ pen_out) {
    pen_out[0] = pen_sum[0] / uniq[0];
}

extern "C" void kernel_launch(void* const* d_in, const int* in_sizes, int n_in,
                              void* d_out, int out_size, void* d_ws, size_t ws_size,
                              hipStream_t stream) {
    const float* x   = (const float*)d_in[0];
    const int*   idx = (const int*)d_in[1];
    const float* Wg  = (const float*)d_in[2];

    float* out   = (float*)d_out;
    float* w_out = out;                                  // NROWS*EEXP floats
    float* pen   = out + (size_t)NROWS * EEXP;           // 1 float

    ushort_t* Whg = (ushort_t*)d_ws;
    ushort_t* Wlg = Whg + (size_t)EEXP * DDIM;
    int* sorted_rows = (int*)(Wlg + (size_t)EEXP * DDIM);
    int* offsets     = sorted_rows + NROWS;
    int* cnt         = offsets + NDOCS + 1;
    int* cursor      = cnt + NDOCS;
    float* pen_sum   = (float*)(cursor + NDOCS);
    float* uniq      = pen_sum + 1;

    init_kernel<<<1, 1024, 0, stream>>>(cnt, pen_sum, uniq);
    hist_kernel<<<HB, 256, 0, stream>>>(idx, cnt);
    scan_kernel<<<1, 1024, 0, stream>>>(cnt, offsets, cursor);
    scatter_kernel<<<HB, 256, 0, stream>>>(idx, cursor, sorted_rows);
    convw_kernel<<<(EEXP * DDIM) / 256, 256, 0, stream>>>(Wg, Whg, Wlg);
    gemm_softmax_kernel<<<NROWS / BM, 256, 0, stream>>>(x, Whg, Wlg, w_out);
    segsum_kernel<<<NDOCS, 256, 0, stream>>>(w_out, sorted_rows, offsets, pen_sum, uniq);
    final_kernel<<<1, 1, 0, stream>>>(pen_sum, uniq, pen);
}

// Round 9
// 367.780 us; speedup vs baseline: 1.5862x; 1.0089x over previous
//
#include <hip/hip_runtime.h>
#include <math.h>

#define NROWS 262144
#define DDIM  1024
#define EEXP  64
#define NDOCS 1024
#define BM    128
#define BK    32
#define HB    64            // hist/scatter blocks
#define RPB   (NROWS / HB)  // rows per hist/scatter block

typedef __attribute__((ext_vector_type(8)))  __bf16 bf16x8;
typedef __attribute__((ext_vector_type(16))) float  f32x16;
typedef unsigned short ushort_t;
typedef unsigned int   uint_t;

// ws layout:
//   Wf ushort[32*8*64*8] = 256 KB   (fragment-major W, hi+lo split)
//   sorted_rows int[NROWS], offsets int[NDOCS+1], cnt int[NDOCS], cursor int[NDOCS]
//   pen_sum f32, uniq f32

__global__ __launch_bounds__(1024) void init_kernel(int* cnt, float* pen_sum, float* uniq) {
    const int t = threadIdx.x;
    cnt[t] = 0;
    if (t == 0) { pen_sum[0] = 0.0f; uniq[0] = 0.0f; }
}

// LDS-privatized histogram: <=NDOCS global atomics per block.
__global__ __launch_bounds__(256) void hist_kernel(const int* __restrict__ idx, int* __restrict__ cnt) {
    __shared__ int lh[NDOCS];
    const int t = threadIdx.x;
    for (int i = t; i < NDOCS; i += 256) lh[i] = 0;
    __syncthreads();
    const int base = blockIdx.x * RPB;
    for (int i = t; i < RPB; i += 256) atomicAdd(&lh[idx[base + i]], 1);
    __syncthreads();
    for (int i = t; i < NDOCS; i += 256) {
        const int c = lh[i];
        if (c) atomicAdd(&cnt[i], c);
    }
}

__global__ __launch_bounds__(1024) void scan_kernel(const int* __restrict__ cnt,
                                                    int* __restrict__ offsets,
                                                    int* __restrict__ cursor) {
    __shared__ int sbuf[NDOCS];
    const int t = threadIdx.x;
    const int my = cnt[t];
    sbuf[t] = my;
    __syncthreads();
    for (int off = 1; off < NDOCS; off <<= 1) {
        int add = (t >= off) ? sbuf[t - off] : 0;
        __syncthreads();
        sbuf[t] += add;
        __syncthreads();
    }
    const int excl = sbuf[t] - my;
    offsets[t] = excl;
    cursor[t]  = excl;
    if (t == NDOCS - 1) offsets[NDOCS] = sbuf[t];
}

// Block-range-reservation scatter: <=NDOCS global atomics per block.
__global__ __launch_bounds__(256) void scatter_kernel(const int* __restrict__ idx,
                                                      int* __restrict__ cursor,
                                                      int* __restrict__ sorted_rows) {
    __shared__ int lh[NDOCS];
    __shared__ int lbase[NDOCS];
    __shared__ int lc[NDOCS];
    const int t = threadIdx.x;
    for (int i = t; i < NDOCS; i += 256) { lh[i] = 0; lc[i] = 0; }
    __syncthreads();
    const int base = blockIdx.x * RPB;
    for (int i = t; i < RPB; i += 256) atomicAdd(&lh[idx[base + i]], 1);
    __syncthreads();
    for (int i = t; i < NDOCS; i += 256) {
        const int c = lh[i];
        if (c) lbase[i] = atomicAdd(&cursor[i], c);
    }
    __syncthreads();
    for (int i = t; i < RPB; i += 256) {
        const int r = base + i;
        const int d = idx[r];
        const int p = atomicAdd(&lc[d], 1);
        sorted_rows[lbase[d] + p] = r;
    }
}

// Build fragment-major W: Wf[((T*8+f)*64+l)*8+j]
//   cl=l&31, hi=l>>5, e = cl + 32*((f>>1)&1), k = T*32 + 16*(f&1) + 8*hi + j
//   f<4 -> hi-bf16 of Wg[e][k]; f>=4 -> lo-bf16 (residual).
__global__ __launch_bounds__(256) void convw_frag_kernel(const float* __restrict__ Wg,
                                                         ushort_t* __restrict__ Wf) {
    const int idx = blockIdx.x * 256 + threadIdx.x;   // 0 .. 131071
    const int j = idx & 7;
    const int l = (idx >> 3) & 63;
    const int f = (idx >> 9) & 7;
    const int T = idx >> 12;
    const int cl = l & 31;
    const int hi = l >> 5;
    const int e  = cl + 32 * ((f >> 1) & 1);
    const int k  = T * 32 + 16 * (f & 1) + 8 * hi + j;
    const float wv = Wg[e * DDIM + k];
    const uint_t b = __float_as_uint(wv);
    ushort_t out;
    if (f < 4) {
        out = (ushort_t)(b >> 16);
    } else {
        const float lov = wv - __uint_as_float(b & 0xFFFF0000u);
        out = (ushort_t)(__float_as_uint(lov) >> 16);
    }
    Wf[idx] = out;
}

__device__ __forceinline__ void gl2lds16(const float* g, float* l) {
    __builtin_amdgcn_global_load_lds(
        (const __attribute__((address_space(1))) void*)g,
        (__attribute__((address_space(3))) void*)l,
        16, 0, 0);
}

#define VMCNT(N)  asm volatile("s_waitcnt vmcnt(" #N ")" ::: "memory")

// BARRIER-FREE MFMA GEMM. BM=128, BK=32, 4 waves; each wave fully independent:
// owns rows 32w..32w+31 (x staged into wave-PRIVATE LDS via global_load_lds,
// depth-2, 3 buffers) and loads its W fragments coalesced from the frag-major
// Wf table in L2 (depth-1, two named reg sets). No __syncthreads anywhere;
// per-wave counted vmcnt only (ledger: 8 W + 4 x issued per iter).
struct WT { bf16x8 h00, h01, h10, h11, m00, m01, m10, m11; };

__global__ __launch_bounds__(256, 2) void gemm_softmax_kernel(
    const float*    __restrict__ x,
    const ushort_t* __restrict__ Wf,
    float*          __restrict__ w_out)
{
    __shared__ float xs[3][4096];   // 3 bufs x (4 waves x 1024 floats private)

    const int t   = threadIdx.x;
    const int w   = t >> 6;
    const int l   = t & 63;
    const int cl  = l & 31;     // A-row-in-wave-tile / B-col / D-col
    const int hi  = l >> 5;     // k-half selector
    const size_t br = (size_t)blockIdx.x * BM;

    const int lrow  = l >> 3;   // 0..7
    const int lunit = l & 7;    // 0..7

    f32x16 acc0 = {};
    f32x16 acc1 = {};
    WT wA, wB;

    union u8b { uint_t u[4]; bf16x8 v; };

#define LOAD_WF(DST, T2) do {                                                          \
        const ushort_t* p_ = Wf + ((size_t)(T2) * 8 * 64 + l) * 8;                     \
        DST.h00 = *(const bf16x8*)(p_ + 0 * 512);                                      \
        DST.h01 = *(const bf16x8*)(p_ + 1 * 512);                                      \
        DST.h10 = *(const bf16x8*)(p_ + 2 * 512);                                      \
        DST.h11 = *(const bf16x8*)(p_ + 3 * 512);                                      \
        DST.m00 = *(const bf16x8*)(p_ + 4 * 512);                                      \
        DST.m01 = *(const bf16x8*)(p_ + 5 * 512);                                      \
        DST.m10 = *(const bf16x8*)(p_ + 6 * 512);                                      \
        DST.m11 = *(const bf16x8*)(p_ + 7 * 512);                                      \
    } while (0)

#define STAGE_X(BUF, k0) do {                                                          \
        float* xb_ = &xs[BUF][w * 1024];                                               \
        _Pragma("unroll")                                                              \
        for (int i_ = 0; i_ < 4; ++i_) {                                               \
            const int row_ = i_ * 8 + lrow;                                            \
            const float* gp_ = x + (br + w * 32 + row_) * DDIM + (k0) + ((lunit ^ lrow) * 4); \
            gl2lds16(gp_, xb_ + i_ * 256);                                             \
        } } while (0)

#define SPLIT8(A, B, AH, AL) do {                                                      \
        const float av_[8] = {A.x, A.y, A.z, A.w, B.x, B.y, B.z, B.w};                 \
        _Pragma("unroll")                                                              \
        for (int p_ = 0; p_ < 4; ++p_) {                                               \
            const uint_t b0_ = __float_as_uint(av_[2 * p_]);                           \
            const uint_t b1_ = __float_as_uint(av_[2 * p_ + 1]);                       \
            AH.u[p_] = (b0_ >> 16) | (b1_ & 0xFFFF0000u);                              \
            const float l0_ = av_[2 * p_]     - __uint_as_float(b0_ & 0xFFFF0000u);    \
            const float l1_ = av_[2 * p_ + 1] - __uint_as_float(b1_ & 0xFFFF0000u);    \
            AL.u[p_] = (__float_as_uint(l0_) >> 16) | (__float_as_uint(l1_) & 0xFFFF0000u); \
        } } while (0)

#define COMPUTE(BUF, WV) do {                                                          \
        const float* xb_ = &xs[BUF][w * 1024];                                         \
        const int sw7_ = cl & 7;                                                       \
        const float4 a0_ = *(const float4*)&xb_[cl * 32 + (((2*hi + 0) ^ sw7_) * 4)];  \
        const float4 a1_ = *(const float4*)&xb_[cl * 32 + (((2*hi + 1) ^ sw7_) * 4)];  \
        const float4 a2_ = *(const float4*)&xb_[cl * 32 + (((4 + 2*hi + 0) ^ sw7_) * 4)]; \
        const float4 a3_ = *(const float4*)&xb_[cl * 32 + (((4 + 2*hi + 1) ^ sw7_) * 4)]; \
        u8b ah0, al0, ah1, al1;                                                        \
        SPLIT8(a0_, a1_, ah0, al0);                                                    \
        SPLIT8(a2_, a3_, ah1, al1);                                                    \
        acc0 = __builtin_amdgcn_mfma_f32_32x32x16_bf16(ah0.v, WV.h00, acc0, 0, 0, 0);  \
        acc1 = __builtin_amdgcn_mfma_f32_32x32x16_bf16(ah0.v, WV.h10, acc1, 0, 0, 0);  \
        acc0 = __builtin_amdgcn_mfma_f32_32x32x16_bf16(ah0.v, WV.m00, acc0, 0, 0, 0);  \
        acc1 = __builtin_amdgcn_mfma_f32_32x32x16_bf16(ah0.v, WV.m10, acc1, 0, 0, 0);  \
        acc0 = __builtin_amdgcn_mfma_f32_32x32x16_bf16(al0.v, WV.h00, acc0, 0, 0, 0);  \
        acc1 = __builtin_amdgcn_mfma_f32_32x32x16_bf16(al0.v, WV.h10, acc1, 0, 0, 0);  \
        acc0 = __builtin_amdgcn_mfma_f32_32x32x16_bf16(ah1.v, WV.h01, acc0, 0, 0, 0);  \
        acc1 = __builtin_amdgcn_mfma_f32_32x32x16_bf16(ah1.v, WV.h11, acc1, 0, 0, 0);  \
        acc0 = __builtin_amdgcn_mfma_f32_32x32x16_bf16(ah1.v, WV.m01, acc0, 0, 0, 0);  \
        acc1 = __builtin_amdgcn_mfma_f32_32x32x16_bf16(ah1.v, WV.m11, acc1, 0, 0, 0);  \
        acc0 = __builtin_amdgcn_mfma_f32_32x32x16_bf16(al1.v, WV.h01, acc0, 0, 0, 0);  \
        acc1 = __builtin_amdgcn_mfma_f32_32x32x16_bf16(al1.v, WV.h11, acc1, 0, 0, 0);  \
    } while (0)

    // ---- prologue: W(0)->A [8], X(0) [4], X(1) [4] ----
    LOAD_WF(wA, 0);
    STAGE_X(0, 0);
    STAGE_X(1, BK);

    // ---- iter 0: issue W(1)->B [8], X(2) [4]; wait X(0): newer = 4+8+4 = 16 ----
    LOAD_WF(wB, 1);
    STAGE_X(2, 2 * BK);
    VMCNT(16);
    COMPUTE(0, wA);

    // ---- pair loop t = 1..28 (steady: newer-than-X(t) = 8+4+8+4 = 24) ----
    int rb = 1;   // read buffer for first iter of pair
    #pragma unroll 1
    for (int tp = 0; tp < 14; ++tp) {
        const int t1 = 2 * tp + 1;
        {   // iter t1 (odd): uses wB, loads W(t1+1)->wA
            const int wb1 = (rb + 2) % 3;
            LOAD_WF(wA, t1 + 1);
            STAGE_X(wb1, (t1 + 2) * BK);
            VMCNT(24);
            COMPUTE(rb, wB);
        }
        const int rb2 = (rb == 2) ? 0 : rb + 1;
        {   // iter t1+1 (even): uses wA, loads W(t1+2)->wB
            const int wb2 = (rb2 + 2) % 3;
            LOAD_WF(wB, t1 + 2);
            STAGE_X(wb2, (t1 + 3) * BK);
            VMCNT(24);
            COMPUTE(rb2, wA);
        }
        rb = (rb2 == 2) ? 0 : rb2 + 1;
    }
    // ---- iter 29 (odd, uses wB): issue W(30)->wA, X(31)->buf1 ----
    LOAD_WF(wA, 30);
    STAGE_X(1, 31 * BK);
    VMCNT(24);
    COMPUTE(2, wB);
    // ---- iter 30 (uses wA): issue W(31)->wB; wait X(30): newer = 8+4+8 = 20 ----
    LOAD_WF(wB, 31);
    VMCNT(20);
    COMPUTE(0, wA);
    // ---- iter 31 (uses wB): wait X(31): newer = 8 ----
    VMCNT(8);
    COMPUTE(1, wB);

    // In-register softmax. D-layout: col = lane&31, row = (r&3) + 8*(r>>2) + 4*hi.
    const size_t orow_base = br + (size_t)w * 32;
    #pragma unroll
    for (int r = 0; r < 16; ++r) {
        const int row = (r & 3) + 8 * (r >> 2) + 4 * hi;
        const float v0 = acc0[r];
        const float v1 = acc1[r];
        float m = fmaxf(v0, v1);
        m = fmaxf(m, __shfl_xor(m, 1));
        m = fmaxf(m, __shfl_xor(m, 2));
        m = fmaxf(m, __shfl_xor(m, 4));
        m = fmaxf(m, __shfl_xor(m, 8));
        m = fmaxf(m, __shfl_xor(m, 16));
        const float e0 = __expf(v0 - m);
        const float e1 = __expf(v1 - m);
        float s = e0 + e1;
        s += __shfl_xor(s, 1);
        s += __shfl_xor(s, 2);
        s += __shfl_xor(s, 4);
        s += __shfl_xor(s, 8);
        s += __shfl_xor(s, 16);
        const float inv = 1.0f / s;
        float* wo = w_out + (orow_base + row) * EEXP;
        wo[cl]      = e0 * inv;
        wo[32 + cl] = e1 * inv;
    }
#undef LOAD_WF
#undef STAGE_X
#undef SPLIT8
#undef COMPUTE
}

// One block per doc. Row list prefetched to LDS to break the load->load chain.
__global__ __launch_bounds__(256) void segsum_kernel(
    const float* __restrict__ w,
    const int*   __restrict__ sorted_rows,
    const int*   __restrict__ offsets,
    float*       __restrict__ pen_sum,
    float*       __restrict__ uniq)
{
    __shared__ int rows_s[512];
    __shared__ float ls1[4][64], ls2[4][64];

    const int d  = blockIdx.x;
    const int t  = threadIdx.x;
    const int e  = t & 63;
    const int rg = t >> 6;
    const int start = offsets[d];
    const int end   = offsets[d + 1];
    const int n     = end - start;

    for (int i = t; i < n && i < 512; i += 256) rows_s[i] = sorted_rows[start + i];
    __syncthreads();

    float s1 = 0.0f, s2 = 0.0f;
    for (int i = rg; i < n; i += 4) {
        const int row = (i < 512) ? rows_s[i] : sorted_rows[start + i];
        const float v = w[(size_t)row * EEXP + e];
        s1 += v;
        s2 += v * v;
    }

    ls1[rg][e] = s1;
    ls2[rg][e] = s2;
    __syncthreads();

    if (t < 64) {
        const float a = ls1[0][e] + ls1[1][e] + ls1[2][e] + ls1[3][e];
        const float b = ls2[0][e] + ls2[1][e] + ls2[2][e] + ls2[3][e];
        const float safe = fmaxf((float)n, 1.0f);
        float contrib = b - a * a / safe;
        #pragma unroll
        for (int off = 32; off > 0; off >>= 1)
            contrib += __shfl_down(contrib, off);
        if (e == 0) {
            if (n > 1) atomicAdd(pen_sum, contrib / (safe * (float)EEXP));
            if (n > 0) atomicAdd(uniq, 1.0f);
        }
    }
}

__global__ void final_kernel(const float* __restrict__ pen_sum,
                             const float* __restrict__ uniq,
                             float* __restrict__ pen_out) {
    pen_out[0] = pen_sum[0] / uniq[0];
}

extern "C" void kernel_launch(void* const* d_in, const int* in_sizes, int n_in,
                              void* d_out, int out_size, void* d_ws, size_t ws_size,
                              hipStream_t stream) {
    const float* x   = (const float*)d_in[0];
    const int*   idx = (const int*)d_in[1];
    const float* Wg  = (const float*)d_in[2];

    float* out   = (float*)d_out;
    float* w_out = out;                                  // NROWS*EEXP floats
    float* pen   = out + (size_t)NROWS * EEXP;           // 1 float

    ushort_t* Wf = (ushort_t*)d_ws;                      // 131072 ushorts = 256 KB
    int* sorted_rows = (int*)(Wf + 131072);
    int* offsets     = sorted_rows + NROWS;
    int* cnt         = offsets + NDOCS + 1;
    int* cursor      = cnt + NDOCS;
    float* pen_sum   = (float*)(cursor + NDOCS);
    float* uniq      = pen_sum + 1;

    init_kernel<<<1, 1024, 0, stream>>>(cnt, pen_sum, uniq);
    hist_kernel<<<HB, 256, 0, stream>>>(idx, cnt);
    scan_kernel<<<1, 1024, 0, stream>>>(cnt, offsets, cursor);
    scatter_kernel<<<HB, 256, 0, stream>>>(idx, cursor, sorted_rows);
    convw_frag_kernel<<<131072 / 256, 256, 0, stream>>>(Wg, Wf);
    gemm_softmax_kernel<<<NROWS / BM, 256, 0, stream>>>(x, Wf, w_out);
    segsum_kernel<<<NDOCS, 256, 0, stream>>>(w_out, sorted_rows, offsets, pen_sum, uniq);
    final_kernel<<<1, 1, 0, stream>>>(pen_sum, uniq, pen);
}